// Round 11
// baseline (162.166 us; speedup 1.0000x reference)
//
#include <hip/hip_runtime.h>

typedef __bf16 bf16;
typedef short s16x8 __attribute__((ext_vector_type(8)));   // 8 bf16 bit-patterns for MFMA frags
typedef __bf16 b16x8 __attribute__((ext_vector_type(8)));  // 8 bf16 for scalar convert paths
typedef float f32x4 __attribute__((ext_vector_type(4)));

#define B_   4096
#define L_   50
#define SH   72               // H row stride (bf16): 64 + 8 pad (2-way bank alias, free)

// ws layout, bf16 elems. Frag-major matrices: frag f = kt*4+nt is a contiguous
// 512-elem (1 KB) block; elem = f*512 + lane*8 + j -> W[k=kt*32+(lane>>4)*8+j][n=nt*16+(lane&15)].
#define OFF_W1F  0            // gv_w1  frag-major, K=128 (16 frags)
#define OFF_W2F  8192         // gv_w2  frag-major, K=64 (8 frags)
#define OFF_W3F  12288        // gv_w3  frag-major
#define OFF_WCF  16384        // (gv_w3 @ att_w1_top) frag-major
#define OFF_A2F  20480        // att_w2 frag-major
#define OFF_R1T  24576        // [64][128] wr1^T row-major (combine tail per-lane dots)
#define OFF_R2T  32768        // [64][64]  wr2^T row-major
#define WT_TOTAL 36864
// byte offsets in ws:
#define BIAS1P_BYTE 73728     // float[64]        att_b1 + gv_b3 @ att_w1_top
#define CQ_BYTE     73984     // float[4096][64]  q_b @ A1_bot  (bias1p added in dense)
#define EU16_BYTE   1122560   // bf16[100000][64] embed_u pre-converted (RNE, same as mkfrag)
#define ER16_BYTE   13922560  // bf16[5][64]      embed_r pre-converted
#define WS_NEED     13923200

#define PREP_W_BLOCKS 145     // ceil((WT_TOTAL+64)/256)
#define CQ_BLOCKS     32      // 4096 items / (4 waves x 32 items) -- MFMA cq
#define CONV_THREADS  800040  // 100000*64/8 + 5*64/8
#define CONV_BLOCKS   3126    // ceil(CONV_THREADS/256)

__device__ __forceinline__ unsigned short f2b(float f) {
    __bf16 h = (__bf16)f;
    return __builtin_bit_cast(unsigned short, h);
}
__device__ __forceinline__ unsigned pack2(float a, float b) {
    return (unsigned)f2b(a) | ((unsigned)f2b(b) << 16);
}
__device__ __forceinline__ s16x8 mkfrag(float4 a, float4 b) {
    union { s16x8 v; unsigned u[4]; } r;
    r.u[0] = pack2(a.x, a.y); r.u[1] = pack2(a.z, a.w);
    r.u[2] = pack2(b.x, b.y); r.u[3] = pack2(b.z, b.w);
    return r.v;
}
__device__ __forceinline__ f32x4 mfma16(s16x8 a, s16x8 b, f32x4 c) {
    return __builtin_amdgcn_mfma_f32_16x16x32_bf16(a, b, c, 0, 0, 0);
}

// -------- prep (single launch): frag-major weights + bias1' + MFMA cq + bf16 embed tables -------
extern "C" __global__ void prep_all(const float* __restrict__ w1, const float* __restrict__ w2,
                                    const float* __restrict__ w3, const float* __restrict__ a1,
                                    const float* __restrict__ a2, const float* __restrict__ r1,
                                    const float* __restrict__ r2, const float* __restrict__ gb3,
                                    const float* __restrict__ ab1,
                                    const int* __restrict__ nodes_v, const float* __restrict__ embed_i,
                                    const float* __restrict__ embed_u, const float* __restrict__ embed_r,
                                    bf16* __restrict__ wt, float* __restrict__ bias1p,
                                    float* __restrict__ cq,
                                    bf16* __restrict__ eu16, bf16* __restrict__ er16)
{
    if (blockIdx.x >= PREP_W_BLOCKS + CQ_BLOCKS) {
        // bf16 conversion of the gather tables (identical RNE rounding to the dense mkfrag path)
        long t = (long)(blockIdx.x - PREP_W_BLOCKS - CQ_BLOCKS) * 256 + threadIdx.x;
        if (t < 800000) {
            const float* s = embed_u + t * 8;
            float4 a = *(const float4*)s, b = *(const float4*)(s + 4);
            *(s16x8*)(eu16 + t * 8) = mkfrag(a, b);
        } else if (t < CONV_THREADS) {
            long r = (t - 800000) * 8;
            const float* s = embed_r + r;
            float4 a = *(const float4*)s, b = *(const float4*)(s + 4);
            *(s16x8*)(er16 + r) = mkfrag(a, b);
        }
        return;
    }
    if (blockIdx.x >= PREP_W_BLOCKS) {
        // cq[i][n] = q_i @ A1_bot via MFMA: wave = 32 items (2 A-tiles), K=64, N=64.
        // B-frags built inline from a1 (L2-hot scalar loads) -> no dependence on wt (no race).
        int wv   = (blockIdx.x - PREP_W_BLOCKS) * 4 + (threadIdx.x >> 6);   // 0..127
        int lane = threadIdx.x & 63, m = lane & 15, quad = lane >> 4;
        int base = wv * 32;
        int i0 = base + m, i1 = base + 16 + m;
        int v0 = nodes_v[i0], v1 = nodes_v[i1];

        s16x8 bfr[8];
#pragma unroll
        for (int kt = 0; kt < 2; ++kt)
#pragma unroll
            for (int nt = 0; nt < 4; ++nt) {
                const float* src = a1 + (64 + kt * 32 + quad * 8) * 64 + nt * 16 + m;
                union { s16x8 v; unsigned u[4]; } fr;
#pragma unroll
                for (int jj = 0; jj < 4; ++jj)
                    fr.u[jj] = pack2(src[(2 * jj) * 64], src[(2 * jj + 1) * 64]);
                bfr[kt * 4 + nt] = fr.v;
            }

        f32x4 ac0[4] = {}, ac1[4] = {};
#pragma unroll
        for (int kt = 0; kt < 2; ++kt) {
            const float* q0 = embed_i + (size_t)v0 * 64 + kt * 32 + quad * 8;
            const float* q1 = embed_i + (size_t)v1 * 64 + kt * 32 + quad * 8;
            s16x8 aq0 = mkfrag(*(const float4*)q0, *(const float4*)(q0 + 4));
            s16x8 aq1 = mkfrag(*(const float4*)q1, *(const float4*)(q1 + 4));
#pragma unroll
            for (int nt = 0; nt < 4; ++nt) {
                ac0[nt] = mfma16(aq0, bfr[kt * 4 + nt], ac0[nt]);
                ac1[nt] = mfma16(aq1, bfr[kt * 4 + nt], ac1[nt]);
            }
        }
#pragma unroll
        for (int nt = 0; nt < 4; ++nt) {
            int c = nt * 16 + m;
#pragma unroll
            for (int r4 = 0; r4 < 4; ++r4) {
                cq[(base + quad * 4 + r4) * 64 + c]      = ac0[nt][r4];
                cq[(base + 16 + quad * 4 + r4) * 64 + c] = ac1[nt][r4];
            }
        }
        return;
    }
    int i = blockIdx.x * 256 + threadIdx.x;
    if (i >= WT_TOTAL + 64) return;
    if (i >= WT_TOTAL) {                       // bias1'[n] = ab1[n] + sum_t gb3[t]*a1[t][n]
        int n = i - WT_TOTAL;
        float s0 = ab1[n], s1 = 0.f, s2 = 0.f, s3 = 0.f;
#pragma unroll
        for (int t = 0; t < 64; t += 4) {
            s0 = fmaf(gb3[t],     a1[t * 64 + n],       s0);
            s1 = fmaf(gb3[t + 1], a1[(t + 1) * 64 + n], s1);
            s2 = fmaf(gb3[t + 2], a1[(t + 2) * 64 + n], s2);
            s3 = fmaf(gb3[t + 3], a1[(t + 3) * 64 + n], s3);
        }
        bias1p[n] = (s0 + s1) + (s2 + s3);
        return;
    }
    float val;
    if (i < OFF_R1T) {
        int off, kind;   // 0=w1,1=w2,2=w3,3=wca,4=a2
        if      (i < OFF_W2F) { off = OFF_W1F; kind = 0; }
        else if (i < OFF_W3F) { off = OFF_W2F; kind = 1; }
        else if (i < OFF_WCF) { off = OFF_W3F; kind = 2; }
        else if (i < OFF_A2F) { off = OFF_WCF; kind = 3; }
        else                  { off = OFF_A2F; kind = 4; }
        int local = i - off;
        int f = local >> 9, lane = (local >> 3) & 63, j = local & 7;
        int kt = f >> 2, nt = f & 3, quad = lane >> 4, m = lane & 15;
        int k = kt * 32 + quad * 8 + j;
        int n = nt * 16 + m;
        if (kind == 0)      val = w1[k * 64 + n];
        else if (kind == 1) val = w2[k * 64 + n];
        else if (kind == 2) val = w3[k * 64 + n];
        else if (kind == 4) val = a2[k * 64 + n];
        else {                                  // wca[k][n] = (W3 @ A1_top)[k][n]
            float s0 = 0.f, s1 = 0.f, s2 = 0.f, s3 = 0.f;
#pragma unroll
            for (int t = 0; t < 64; t += 4) {
                float4 w = *(const float4*)(w3 + k * 64 + t);
                s0 = fmaf(w.x, a1[t * 64 + n],       s0);
                s1 = fmaf(w.y, a1[(t + 1) * 64 + n], s1);
                s2 = fmaf(w.z, a1[(t + 2) * 64 + n], s2);
                s3 = fmaf(w.w, a1[(t + 3) * 64 + n], s3);
            }
            val = (s0 + s1) + (s2 + s3);
        }
    }
    else if (i < OFF_R2T) { int li = i - OFF_R1T; int n = li >> 7, k = li & 127; val = r1[k * 64 + n]; }
    else                  { int li = i - OFF_R2T; int n = li >> 6, k = li & 63;  val = r2[k * 64 + n]; }
    wt[i] = (bf16)val;
}

// ---------------- fused: ONE ITEM PER WAVE, 4 waves/block (256 thr), ZERO barriers ----------------
// R4's verified-correct dataflow (each wave owns all 50 neighbors of one item as 4 A-tiles;
// in-wave softmax; in-wave tail) with its two failure causes fixed: 256-thread blocks (dispatch
// granularity, grid 1024) and __launch_bounds__(256,2) (VGPR cap 256 -- R4's (64,3) cap forced a
// 107 B/thread scratch spill, WRITE_SIZE 28 MB). Frag-load traffic per item is HALVED vs the
// 2-tile-wave structure: 48 B-frag loads now feed 4 tiles' MFMA instead of 2.
template<bool BF16E>
__global__ void __launch_bounds__(256, 2)
dense_fused(const int* __restrict__ nodes_v, const int* __restrict__ neigh_u,
            const int* __restrict__ neigh_r,
            const float* __restrict__ embed_u, const float* __restrict__ embed_i,
            const float* __restrict__ embed_r,
            const float* __restrict__ gv_b1, const float* __restrict__ gv_b2,
            const float* __restrict__ gv_b3,
            const float* __restrict__ att_b2, const float* __restrict__ att_w3,
            const float* __restrict__ wr1_b, const float* __restrict__ wr2_b,
            const bf16* __restrict__ wt, const bf16* __restrict__ eu16,
            const bf16* __restrict__ er16, const float* __restrict__ cq,
            const float* __restrict__ bias1p, float* __restrict__ out)
{
    __shared__ __align__(16) bf16 H[4 * 64 * SH];   // 36.9 KB: per-wave 64-row tile, no sharing

    const int tid = threadIdx.x;
    const int lane = tid & 63, wave = tid >> 6;
    const int m = lane & 15, quad = lane >> 4;
    const int b = blockIdx.x * 4 + wave;            // this wave's item

    bf16* Hw = H + wave * 64 * SH;                  // wave-private 64 rows

    // neighbor indices for this lane's 4 A-frag rows (clamped; pad rows masked at softmax)
    int un[4], vn[4];
#pragma unroll
    for (int t = 0; t < 4; ++t) {
        int l = min(t * 16 + m, L_ - 1);
        un[t] = neigh_u[b * L_ + l];
        vn[t] = neigh_r[b * L_ + l];
    }

    // att1 per-item bias, per-lane; L1/L2-hot
    float cs4[4];
#pragma unroll
    for (int nt = 0; nt < 4; ++nt) {
        int c = nt * 16 + m;
        cs4[nt] = cq[b * 64 + c] + bias1p[c];
    }

    // ---- gv1: h1 = relu([pt|er] @ W1 + b1) -> Hw ----
    {
        f32x4 ac[4][4] = {};   // [tile][nt]
#pragma unroll
        for (int kt = 0; kt < 4; ++kt) {
            s16x8 bfr[4];
#pragma unroll
            for (int nt = 0; nt < 4; ++nt)
                bfr[nt] = *(const s16x8*)(wt + OFF_W1F + (kt * 4 + nt) * 512 + lane * 8);
#pragma unroll
            for (int t = 0; t < 4; ++t) {
                s16x8 a;
                if constexpr (BF16E) {
                    const bf16* src = (kt < 2 ? eu16 + (size_t)un[t] * 64
                                              : er16 + (size_t)vn[t] * 64)
                                      + (kt & 1) * 32 + quad * 8;
                    a = *(const s16x8*)src;
                } else {
                    const float* src = (kt < 2 ? embed_u + (size_t)un[t] * 64
                                               : embed_r + (size_t)vn[t] * 64)
                                       + (kt & 1) * 32 + quad * 8;
                    a = mkfrag(*(const float4*)src, *(const float4*)(src + 4));
                }
#pragma unroll
                for (int nt = 0; nt < 4; ++nt)
                    ac[t][nt] = mfma16(a, bfr[nt], ac[t][nt]);
            }
        }
#pragma unroll
        for (int nt = 0; nt < 4; ++nt) {
            int c = nt * 16 + m;
            float bv = gv_b1[c];
#pragma unroll
            for (int t = 0; t < 4; ++t)
#pragma unroll
                for (int r4 = 0; r4 < 4; ++r4)
                    Hw[(t * 16 + quad * 4 + r4) * SH + c] = (bf16)fmaxf(ac[t][nt][r4] + bv, 0.f);
        }
    }

    // ---- gv2: h1 -> h2 (in-place, same-wave WAR safe) ----
    {
        f32x4 ac[4][4] = {};
#pragma unroll
        for (int kt = 0; kt < 2; ++kt) {
            s16x8 bfr[4];
#pragma unroll
            for (int nt = 0; nt < 4; ++nt)
                bfr[nt] = *(const s16x8*)(wt + OFF_W2F + (kt * 4 + nt) * 512 + lane * 8);
#pragma unroll
            for (int t = 0; t < 4; ++t) {
                s16x8 a = *(const s16x8*)(Hw + (t * 16 + m) * SH + kt * 32 + quad * 8);
#pragma unroll
                for (int nt = 0; nt < 4; ++nt)
                    ac[t][nt] = mfma16(a, bfr[nt], ac[t][nt]);
            }
        }
#pragma unroll
        for (int nt = 0; nt < 4; ++nt) {
            int c = nt * 16 + m;
            float bv = gv_b2[c];
#pragma unroll
            for (int t = 0; t < 4; ++t)
#pragma unroll
                for (int r4 = 0; r4 < 4; ++r4)
                    Hw[(t * 16 + quad * 4 + r4) * SH + c] = (bf16)fmaxf(ac[t][nt][r4] + bv, 0.f);
        }
    }

    // ---- fused gv3 + att1': consume h2; fjt stays in regs (aF), att1h -> Hw ----
    f32x4 aF[4][4] = {};
    {
        f32x4 aA[4][4] = {};
#pragma unroll
        for (int kt = 0; kt < 2; ++kt) {
            s16x8 bF[4], bA[4];
#pragma unroll
            for (int nt = 0; nt < 4; ++nt) {
                bF[nt] = *(const s16x8*)(wt + OFF_W3F + (kt * 4 + nt) * 512 + lane * 8);
                bA[nt] = *(const s16x8*)(wt + OFF_WCF + (kt * 4 + nt) * 512 + lane * 8);
            }
#pragma unroll
            for (int t = 0; t < 4; ++t) {
                s16x8 a = *(const s16x8*)(Hw + (t * 16 + m) * SH + kt * 32 + quad * 8);
#pragma unroll
                for (int nt = 0; nt < 4; ++nt) {
                    aF[t][nt] = mfma16(a, bF[nt], aF[t][nt]);
                    aA[t][nt] = mfma16(a, bA[nt], aA[t][nt]);
                }
            }
        }
        // write only att1h; aF kept in regs (gv_b3 folded into zj via sum(mu)==1)
#pragma unroll
        for (int nt = 0; nt < 4; ++nt) {
            int c = nt * 16 + m;
#pragma unroll
            for (int t = 0; t < 4; ++t)
#pragma unroll
                for (int r4 = 0; r4 < 4; ++r4)
                    Hw[(t * 16 + quad * 4 + r4) * SH + c] = (bf16)fmaxf(aA[t][nt][r4] + cs4[nt], 0.f);
        }
    }

    // ---- att2 + relu + dot(att_w3) + m-reduce -> per-row scores (m-uniform per quad) ----
    float sc[4][4];   // [tile][r4]
    {
        f32x4 ac[4][4] = {};
#pragma unroll
        for (int kt = 0; kt < 2; ++kt) {
            s16x8 bfr[4];
#pragma unroll
            for (int nt = 0; nt < 4; ++nt)
                bfr[nt] = *(const s16x8*)(wt + OFF_A2F + (kt * 4 + nt) * 512 + lane * 8);
#pragma unroll
            for (int t = 0; t < 4; ++t) {
                s16x8 a = *(const s16x8*)(Hw + (t * 16 + m) * SH + kt * 32 + quad * 8);
#pragma unroll
                for (int nt = 0; nt < 4; ++nt)
                    ac[t][nt] = mfma16(a, bfr[nt], ac[t][nt]);
            }
        }
#pragma unroll
        for (int t = 0; t < 4; ++t)
#pragma unroll
            for (int r4 = 0; r4 < 4; ++r4) sc[t][r4] = 0.f;
#pragma unroll
        for (int nt = 0; nt < 4; ++nt) {
            int c = nt * 16 + m;
            float b2v = att_b2[c], w3v = att_w3[c];
#pragma unroll
            for (int t = 0; t < 4; ++t)
#pragma unroll
                for (int r4 = 0; r4 < 4; ++r4)
                    sc[t][r4] += fmaxf(ac[t][nt][r4] + b2v, 0.f) * w3v;
        }
#pragma unroll
        for (int mask = 1; mask < 16; mask <<= 1)
#pragma unroll
            for (int t = 0; t < 4; ++t)
#pragma unroll
                for (int r4 = 0; r4 < 4; ++r4)
                    sc[t][r4] += __shfl_xor(sc[t][r4], mask);
    }

    // ---- in-wave softmax over the 50 real rows + e-weighted fjt sum ----
    float z[4], ssum;
    {
        float mloc = -1e30f;
#pragma unroll
        for (int t = 0; t < 4; ++t)
#pragma unroll
            for (int r4 = 0; r4 < 4; ++r4)
                if (t * 16 + quad * 4 + r4 < L_) mloc = fmaxf(mloc, sc[t][r4]);
        mloc = fmaxf(mloc, __shfl_xor(mloc, 16));
        mloc = fmaxf(mloc, __shfl_xor(mloc, 32));

        float e[4][4];
        ssum = 0.f;
#pragma unroll
        for (int t = 0; t < 4; ++t)
#pragma unroll
            for (int r4 = 0; r4 < 4; ++r4) {
                e[t][r4] = (t * 16 + quad * 4 + r4 < L_) ? __expf(sc[t][r4] - mloc) : 0.f;
                ssum += e[t][r4];
            }
        ssum += __shfl_xor(ssum, 16);
        ssum += __shfl_xor(ssum, 32);

#pragma unroll
        for (int nt = 0; nt < 4; ++nt) z[nt] = 0.f;
#pragma unroll
        for (int t = 0; t < 4; ++t)
#pragma unroll
            for (int r4 = 0; r4 < 4; ++r4)
#pragma unroll
                for (int nt = 0; nt < 4; ++nt)
                    z[nt] += aF[t][nt][r4] * e[t][r4];
#pragma unroll
        for (int nt = 0; nt < 4; ++nt) {
            z[nt] += __shfl_xor(z[nt], 16);
            z[nt] += __shfl_xor(z[nt], 32);
        }
    }

    // ---- tail (all in-wave): zj -> combine MLP -> out. Overlay wave's H as float share bufs. ----
    {
        float* zsh = (float*)Hw;         // Hw is dead; lockstep wave => in-order LDS reuse safe
        float* qsh = zsh + 64;
#pragma unroll
        for (int nt = 0; nt < 4; ++nt) {
            int c = nt * 16 + m;
            zsh[c] = z[nt] / ssum + gv_b3[c];
        }
        const int d = lane;
        qsh[d] = embed_i[(size_t)nodes_v[b] * 64 + d];

        // z2 = relu([zj|q] @ wr1 + b1)   (2 accumulators to shorten the fmaf chain)
        float p0 = wr1_b[d], p1 = 0.f;
        const bf16* r1 = wt + OFF_R1T + d * 128;
#pragma unroll
        for (int k8 = 0; k8 < 8; ++k8) {
            b16x8 wv = *(const b16x8*)(r1 + k8 * 8);
#pragma unroll
            for (int j = 0; j < 8; j += 2) {
                p0 = fmaf((float)wv[j],     zsh[k8 * 8 + j],     p0);
                p1 = fmaf((float)wv[j + 1], zsh[k8 * 8 + j + 1], p1);
            }
        }
#pragma unroll
        for (int k8 = 0; k8 < 8; ++k8) {
            b16x8 wv = *(const b16x8*)(r1 + 64 + k8 * 8);
#pragma unroll
            for (int j = 0; j < 8; j += 2) {
                p0 = fmaf((float)wv[j],     qsh[k8 * 8 + j],     p0);
                p1 = fmaf((float)wv[j + 1], qsh[k8 * 8 + j + 1], p1);
            }
        }
        zsh[d] = fmaxf(p0 + p1, 0.f);   // all zsh/qsh reads above retire first (lockstep)

        // out = relu(z2 @ wr2 + b2)
        float q0 = wr2_b[d], q1 = 0.f;
        const bf16* r2 = wt + OFF_R2T + d * 64;
#pragma unroll
        for (int k8 = 0; k8 < 8; ++k8) {
            b16x8 wv = *(const b16x8*)(r2 + k8 * 8);
#pragma unroll
            for (int j = 0; j < 8; j += 2) {
                q0 = fmaf((float)wv[j],     zsh[k8 * 8 + j],     q0);
                q1 = fmaf((float)wv[j + 1], zsh[k8 * 8 + j + 1], q1);
            }
        }
        out[(size_t)b * 64 + d] = fmaxf(q0 + q1, 0.f);
    }
}

extern "C" void kernel_launch(void* const* d_in, const int* in_sizes, int n_in,
                              void* d_out, int out_size, void* d_ws, size_t ws_size,
                              hipStream_t stream)
{
    const int* nodes_v = (const int*)d_in[0];
    const int* neigh_u = (const int*)d_in[1];
    const int* neigh_r = (const int*)d_in[2];
    const float* embed_u = (const float*)d_in[3];
    const float* embed_i = (const float*)d_in[4];
    const float* embed_r = (const float*)d_in[5];
    const float* gv_w1  = (const float*)d_in[6];  const float* gv_b1 = (const float*)d_in[7];
    const float* gv_w2  = (const float*)d_in[8];  const float* gv_b2 = (const float*)d_in[9];
    const float* gv_w3  = (const float*)d_in[10]; const float* gv_b3 = (const float*)d_in[11];
    const float* att_w1 = (const float*)d_in[12]; const float* att_b1 = (const float*)d_in[13];
    const float* att_w2 = (const float*)d_in[14]; const float* att_b2 = (const float*)d_in[15];
    const float* att_w3 = (const float*)d_in[16]; const float* att_b3 = (const float*)d_in[17];
    const float* wr1_w  = (const float*)d_in[18]; const float* wr1_b = (const float*)d_in[19];
    const float* wr2_w  = (const float*)d_in[20]; const float* wr2_b = (const float*)d_in[21];
    (void)att_b3;  // softmax shift-invariance

    bf16*  wt     = (bf16*)d_ws;
    float* bias1p = (float*)((char*)d_ws + BIAS1P_BYTE);
    float* cq     = (float*)((char*)d_ws + CQ_BYTE);
    bf16*  eu16   = (bf16*)((char*)d_ws + EU16_BYTE);
    bf16*  er16   = (bf16*)((char*)d_ws + ER16_BYTE);

    const bool big = ws_size >= (size_t)WS_NEED;
    const int prep_grid = PREP_W_BLOCKS + CQ_BLOCKS + (big ? CONV_BLOCKS : 0);

    prep_all<<<prep_grid, 256, 0, stream>>>(
        gv_w1, gv_w2, gv_w3, att_w1, att_w2, wr1_w, wr2_w, gv_b3, att_b1,
        nodes_v, embed_i, embed_u, embed_r, wt, bias1p, cq, eu16, er16);

    if (big) {
        dense_fused<true><<<B_ / 4, 256, 0, stream>>>(nodes_v, neigh_u, neigh_r,
                                                      embed_u, embed_i, embed_r,
                                                      gv_b1, gv_b2, gv_b3, att_b2, att_w3,
                                                      wr1_b, wr2_b, wt, eu16, er16,
                                                      cq, bias1p, (float*)d_out);
    } else {
        dense_fused<false><<<B_ / 4, 256, 0, stream>>>(nodes_v, neigh_u, neigh_r,
                                                       embed_u, embed_i, embed_r,
                                                       gv_b1, gv_b2, gv_b3, att_b2, att_w3,
                                                       wr1_b, wr2_b, wt, eu16, er16,
                                                       cq, bias1p, (float*)d_out);
    }
}